// Round 7
// baseline (981.507 us; speedup 1.0000x reference)
//
#include <hip/hip_runtime.h>
#include <hip/hip_bf16.h>
#include <cstddef>
#include <cstdint>

#define T_TOK 1024
#define HDIM  2048
#define NEXP  64
#define IDIM  768
#define TOPK  8

using f32x4 = __attribute__((ext_vector_type(4))) float;
using s16x8 = __attribute__((ext_vector_type(8))) short;

// ---- workspace layout (bytes) ----
static constexpr size_t XBF_OFF = 0;                                   // bf16 X: 4 MiB
static constexpr size_t CNT_OFF = (size_t)T_TOK * HDIM * 2;            // 64 ints
static constexpr size_t OFF_OFF = CNT_OFF + 256;                       // 65 ints
static constexpr size_t QM_OFF  = CNT_OFF + 768;                       // q_gu, q_dn, nrg
static constexpr size_t RGL_OFF = CNT_OFF + 1024;                      // rowgroup list
static constexpr size_t TOK_OFF = CNT_OFF + 4096;                      // 64*1024 ints
static constexpr size_t WT_OFF  = TOK_OFF + (size_t)NEXP * T_TOK * 4;  // 64*1024 floats
static constexpr size_t HH_OFF  = WT_OFF  + (size_t)NEXP * T_TOK * 4;  // 8192*768 bf16

__device__ __forceinline__ short f2bf(float f) {
  union { __hip_bfloat16 b; short s; } u;
  u.b = __float2bfloat16(f);
  return u.s;
}
__device__ __forceinline__ uint32_t pk2(float lo, float hi) {
  return ((uint32_t)(uint16_t)f2bf(hi) << 16) | (uint16_t)f2bf(lo);
}
__device__ __forceinline__ void barrier_raw() {
  asm volatile("" ::: "memory");
  __builtin_amdgcn_s_barrier();
  asm volatile("" ::: "memory");
}
#define WAIT_LGKM0() asm volatile("s_waitcnt lgkmcnt(0)" ::: "memory")

// ---------------- router (+ fused fp32->bf16 convert of X) ----------------
__global__ __launch_bounds__(256) void router_kernel(
    const float* __restrict__ X, const float* __restrict__ GW,
    __hip_bfloat16* __restrict__ Xb,
    int* __restrict__ cnt, int* __restrict__ tokl, float* __restrict__ wtl) {
  __shared__ float xs[HDIM];
  __shared__ float lg[NEXP];
  const int t = blockIdx.x;
  const int tid = threadIdx.x;
  const f32x4* xr = (const f32x4*)(X + (size_t)t * HDIM);
#pragma unroll
  for (int i = 0; i < 2; ++i) {
    f32x4 v = xr[tid + i * 256];
    *(f32x4*)&xs[(tid + i * 256) * 4] = v;
  }
  __syncthreads();
  {
    union { short h[8]; int4 q; } u;
#pragma unroll
    for (int j = 0; j < 8; ++j) u.h[j] = f2bf(xs[tid * 8 + j]);
    *(int4*)((char*)Xb + ((size_t)t * HDIM + tid * 8) * 2) = u.q;
  }
  const int wid = tid >> 6, lane = tid & 63;
  for (int ee = 0; ee < 16; ++ee) {
    const int e = wid * 16 + ee;
    const float* g = GW + (size_t)e * HDIM;
    float acc = 0.f;
    for (int i = lane; i < HDIM; i += 64) acc += xs[i] * g[i];
#pragma unroll
    for (int s = 32; s; s >>= 1) acc += __shfl_xor(acc, s);
    if (lane == 0) lg[e] = acc;
  }
  __syncthreads();
  if (tid < 64) {
    const float v = lg[tid];
    float m = v;
#pragma unroll
    for (int s = 32; s; s >>= 1) m = fmaxf(m, __shfl_xor(m, s));
    const float p = expf(v - m);
    float den = p;
#pragma unroll
    for (int s = 32; s; s >>= 1) den += __shfl_xor(den, s);
    float work = p / den;
    float my_v = 0.f; int my_e = 0;
    float topsum = 0.f;
#pragma unroll
    for (int k = 0; k < TOPK; ++k) {
      float mv = work;
#pragma unroll
      for (int s = 32; s; s >>= 1) mv = fmaxf(mv, __shfl_xor(mv, s));
      unsigned long long ball = __ballot(work == mv);
      const int idx = __ffsll(ball) - 1;   // lowest index on ties (matches lax.top_k)
      topsum += mv;
      if (tid == k) { my_v = mv; my_e = idx; }
      if (tid == idx) work = -1.f;
    }
    if (tid < TOPK) {
      const float w = my_v / topsum;
      const int slot = atomicAdd(&cnt[my_e], 1);
      tokl[my_e * T_TOK + slot] = t;
      wtl[my_e * T_TOK + slot] = w;
    }
  }
}

// ---------------- prefix scan + rowgroup list ----------------
__global__ void scan_kernel(const int* __restrict__ cnt, int* __restrict__ offs,
                            int* __restrict__ rgl, int* __restrict__ qm) {
  if (threadIdx.x == 0) {
    int a = 0, nrg = 0;
    for (int e = 0; e < NEXP; ++e) {
      offs[e] = a;
      const int ne = cnt[e];
      a += ne;
      for (int t = 0; t * 128 < ne; ++t) rgl[nrg++] = (e << 3) | t;
    }
    offs[NEXP] = a;
    qm[2] = nrg;
  }
}

// ================= gate+up GEMM + SwiGLU =================
// item = (rowgroup, nc of 12): BM=128, BN=64 per matrix, both mats, BK=32.
// Reg-staged pipeline: global fp32/bf16 -> 4 named reg sets (depth 3) ->
// cvt+pack bf16 -> LDS double-buffer (2x16896B) -> b128/b32 frag reads.
// Two raw asm barriers/step pin the schedule; no __syncthreads, no manual
// vmcnt in the K-loop (compiler emits exact per-reg waits at ds_write).
#define GU_STEPS 64

__global__ __launch_bounds__(256, 2) void gateup_kernel(
    const __hip_bfloat16* __restrict__ Xb, const float* __restrict__ WG,
    const float* __restrict__ WU, const int* __restrict__ cnt,
    const int* __restrict__ offs, const int* __restrict__ tokl,
    const float* __restrict__ wtl, __hip_bfloat16* __restrict__ Hh,
    int* __restrict__ qm, const int* __restrict__ rgl) {
  __shared__ __align__(16) char sL[2][16896];   // A 8192 + B 2*4352
  __shared__ int sItem;
  const int tid = threadIdx.x, lane = tid & 63, wid = tid >> 6;
  const int m = lane >> 4, c = lane & 15;
  // A staging: 2 insts x 16 rows; storage [row][slot*16B], slot = chunk^(row&3)
  const int asr  = wid * 32 + (lane >> 2);
  const int achk = (lane & 3) ^ ((lane >> 2) & 3);
  const int adst = wid * 2048 + lane * 16;
  // B staging: wave pair per mat; lane holds 4 consecutive k-rows x 4n fp32
  const int bg   = (lane >> 4) & 3;
  const int bk0  = (wid & 1) * 16 + bg * 4;
  const int bdst = 8192 + (wid >> 1) * 4352 + ((wid & 1) * 8 + bg * 2) * 272 + (lane & 15) * 16;
  // fragment offsets
  int aoffs[2];
#pragma unroll
  for (int mi = 0; mi < 2; ++mi)
    aoffs[mi] = (wid * 32 + mi * 16 + c) * 64 + ((m ^ (c & 3)) << 4);
  int boffs[2][4];
#pragma unroll
  for (int mt = 0; mt < 2; ++mt)
#pragma unroll
    for (int nf = 0; nf < 4; ++nf)
      boffs[mt][nf] = 8192 + mt * 4352 + (m * 4) * 272 + (nf * 16 + c) * 4;
  const int itot = qm[2] * 12;

  for (;;) {
    __syncthreads();
    if (tid == 0) sItem = atomicAdd(&qm[0], 1);
    __syncthreads();
    const int it = sItem;
    if (it >= itot) break;
    const int rg = rgl[it / 12];
    const int e = rg >> 3, ti = rg & 7, nc = it % 12;
    const int ne = cnt[e];
    const int nrows = min(128, ne - ti * 128);
    const int nb = nc * 64;
    const int cbase = offs[e] + ti * 128;
    const int tbase = e * T_TOK + ti * 128;

    const short* pa0 = (const short*)Xb + (size_t)tokl[tbase + min(asr, nrows - 1)] * HDIM + achk * 8;
    const short* pa1 = (const short*)Xb + (size_t)tokl[tbase + min(asr + 16, nrows - 1)] * HDIM + achk * 8;
    const float* pb = ((wid >> 1) ? WU : WG) + (size_t)e * HDIM * IDIM
                      + (size_t)bk0 * IDIM + nb + (lane & 15) * 4;

    f32x4 acc[2][2][4];
#pragma unroll
    for (int i = 0; i < 2; ++i)
#pragma unroll
      for (int mt = 0; mt < 2; ++mt)
#pragma unroll
        for (int nf = 0; nf < 4; ++nf)
#pragma unroll
          for (int r = 0; r < 4; ++r) acc[i][mt][nf][r] = 0.f;

    int4 aS[4][2];
    f32x4 bS[4][4];

    auto LOAD = [&](int4& x0, int4& x1, f32x4 (&b)[4]) {
      x0 = *(const int4*)pa0;
      x1 = *(const int4*)pa1;
      pa0 += 32; pa1 += 32;
#pragma unroll
      for (int i = 0; i < 4; ++i) b[i] = *(const f32x4*)(pb + (size_t)i * IDIM);
      pb += (size_t)32 * IDIM;
    };
    auto WRITE = [&](int buf, const int4& x0, const int4& x1, const f32x4 (&b)[4]) {
      char* base = sL[buf];
      *(int4*)(base + adst) = x0;
      *(int4*)(base + adst + 1024) = x1;
      union { uint32_t u4[4]; int4 q; } d0, d1;
#pragma unroll
      for (int n = 0; n < 4; ++n) {
        d0.u4[n] = pk2(b[0][n], b[1][n]);
        d1.u4[n] = pk2(b[2][n], b[3][n]);
      }
      *(int4*)(base + bdst) = d0.q;
      *(int4*)(base + bdst + 272) = d1.q;
    };

    // prologue: tiles 0..3 into sets; tile0 -> buf0
    LOAD(aS[0][0], aS[0][1], bS[0]);
    LOAD(aS[1][0], aS[1][1], bS[1]);
    LOAD(aS[2][0], aS[2][1], bS[2]);
    LOAD(aS[3][0], aS[3][1], bS[3]);
    WRITE(0, aS[0][0], aS[0][1], bS[0]);
    WAIT_LGKM0();
    barrier_raw();

    for (int itr = 0; itr < GU_STEPS / 4; ++itr) {
#pragma unroll
      for (int u = 0; u < 4; ++u) {
        const int t = itr * 4 + u;
        const char* bb = sL[t & 1];
        if (t + 4 < GU_STEPS) LOAD(aS[u][0], aS[u][1], bS[u]);   // tile t+4 -> slot t&3==u
        s16x8 af0 = *(const s16x8*)(bb + aoffs[0]);
        s16x8 af1 = *(const s16x8*)(bb + aoffs[1]);
        s16x8 bf[2][4];
#pragma unroll
        for (int mt = 0; mt < 2; ++mt)
#pragma unroll
          for (int nf = 0; nf < 4; ++nf) {
            const char* p = bb + boffs[mt][nf];
            union { uint32_t u4[4]; s16x8 v; } w;
            w.u4[0] = *(const uint32_t*)p;
            w.u4[1] = *(const uint32_t*)(p + 272);
            w.u4[2] = *(const uint32_t*)(p + 544);
            w.u4[3] = *(const uint32_t*)(p + 816);
            bf[mt][nf] = w.v;
          }
        WAIT_LGKM0();
        barrier_raw();                                    // reads of buf(t&1) done
        if (t + 1 < GU_STEPS)
          WRITE((t + 1) & 1, aS[(u + 1) & 3][0], aS[(u + 1) & 3][1], bS[(u + 1) & 3]);
        WAIT_LGKM0();
        barrier_raw();                                    // writes of buf((t+1)&1) visible
#pragma unroll
        for (int mt = 0; mt < 2; ++mt)
#pragma unroll
          for (int nf = 0; nf < 4; ++nf) {
            acc[0][mt][nf] = __builtin_amdgcn_mfma_f32_16x16x32_bf16(af0, bf[mt][nf], acc[0][mt][nf], 0, 0, 0);
            acc[1][mt][nf] = __builtin_amdgcn_mfma_f32_16x16x32_bf16(af1, bf[mt][nf], acc[1][mt][nf], 0, 0, 0);
          }
      }
    }

    // epilogue: h = silu(g) * u * wt -> bf16 Hh (compact rows)
#pragma unroll
    for (int mi = 0; mi < 2; ++mi) {
      const int rb = wid * 32 + mi * 16 + m * 4;
      const f32x4 wt4 = *(const f32x4*)&wtl[tbase + rb];
#pragma unroll
      for (int nf = 0; nf < 4; ++nf) {
        const int colg = nb + nf * 16 + c;
#pragma unroll
        for (int r = 0; r < 4; ++r) {
          const int row = rb + r;
          if (row < nrows) {
            const float g = acc[mi][0][nf][r], uu = acc[mi][1][nf][r];
            const float h = (g / (1.f + __expf(-g))) * uu * wt4[r];
            Hh[(size_t)(cbase + row) * IDIM + colg] = __float2bfloat16(h);
          }
        }
      }
    }
  }
}

// ================= down GEMM + scatter =================
// item = (rowgroup, hc of 16): BM=128, BN=128, BK=32, 24 steps. Same pipeline.
#define DN_STEPS 24

__global__ __launch_bounds__(256, 2) void down_kernel(
    const __hip_bfloat16* __restrict__ Hh, const float* __restrict__ WD,
    const int* __restrict__ cnt, const int* __restrict__ offs,
    const int* __restrict__ tokl, float* __restrict__ Out,
    int* __restrict__ qm, const int* __restrict__ rgl) {
  __shared__ __align__(16) char sL[2][16640];   // A 8192 + B 16*528
  __shared__ int sItem;
  const int tid = threadIdx.x, lane = tid & 63, wid = tid >> 6;
  const int m = lane >> 4, c = lane & 15;
  const int asr  = wid * 32 + (lane >> 2);
  const int achk = (lane & 3) ^ ((lane >> 2) & 3);
  const int adst = wid * 2048 + lane * 16;
  const int bg   = (lane >> 5) & 1;
  const int bdst = 8192 + (wid * 4 + bg * 2) * 528 + (lane & 31) * 16;
  int aoffs[2];
#pragma unroll
  for (int mi = 0; mi < 2; ++mi)
    aoffs[mi] = (wid * 32 + mi * 16 + c) * 64 + ((m ^ (c & 3)) << 4);
  int boffs[8];
#pragma unroll
  for (int nf = 0; nf < 8; ++nf)
    boffs[nf] = 8192 + (m * 4) * 528 + (nf * 16 + c) * 4;
  const int itot = qm[2] * 16;

  for (;;) {
    __syncthreads();
    if (tid == 0) sItem = atomicAdd(&qm[1], 1);
    __syncthreads();
    const int it = sItem;
    if (it >= itot) break;
    const int rg = rgl[it >> 4];
    const int e = rg >> 3, ti = rg & 7, hc = it & 15;
    const int ne = cnt[e];
    const int nrows = min(128, ne - ti * 128);
    const int hb = hc * 128;
    const int cbase = offs[e] + ti * 128;
    const int tbase = e * T_TOK + ti * 128;

    const short* pa0 = (const short*)Hh + (size_t)(cbase + min(asr, nrows - 1)) * IDIM + achk * 8;
    const short* pa1 = (const short*)Hh + (size_t)(cbase + min(asr + 16, nrows - 1)) * IDIM + achk * 8;
    const float* pb = WD + (size_t)e * IDIM * HDIM
                      + (size_t)(wid * 8 + bg * 4) * HDIM + hb + (lane & 31) * 4;

    f32x4 acc[2][8];
#pragma unroll
    for (int i = 0; i < 2; ++i)
#pragma unroll
      for (int nf = 0; nf < 8; ++nf)
#pragma unroll
        for (int r = 0; r < 4; ++r) acc[i][nf][r] = 0.f;

    int4 aS[4][2];
    f32x4 bS[4][4];

    auto LOAD = [&](int4& x0, int4& x1, f32x4 (&b)[4]) {
      x0 = *(const int4*)pa0;
      x1 = *(const int4*)pa1;
      pa0 += 32; pa1 += 32;
#pragma unroll
      for (int i = 0; i < 4; ++i) b[i] = *(const f32x4*)(pb + (size_t)i * HDIM);
      pb += (size_t)32 * HDIM;
    };
    auto WRITE = [&](int buf, const int4& x0, const int4& x1, const f32x4 (&b)[4]) {
      char* base = sL[buf];
      *(int4*)(base + adst) = x0;
      *(int4*)(base + adst + 1024) = x1;
      union { uint32_t u4[4]; int4 q; } d0, d1;
#pragma unroll
      for (int n = 0; n < 4; ++n) {
        d0.u4[n] = pk2(b[0][n], b[1][n]);
        d1.u4[n] = pk2(b[2][n], b[3][n]);
      }
      *(int4*)(base + bdst) = d0.q;
      *(int4*)(base + bdst + 528) = d1.q;
    };

    LOAD(aS[0][0], aS[0][1], bS[0]);
    LOAD(aS[1][0], aS[1][1], bS[1]);
    LOAD(aS[2][0], aS[2][1], bS[2]);
    LOAD(aS[3][0], aS[3][1], bS[3]);
    WRITE(0, aS[0][0], aS[0][1], bS[0]);
    WAIT_LGKM0();
    barrier_raw();

    for (int itr = 0; itr < DN_STEPS / 4; ++itr) {
#pragma unroll
      for (int u = 0; u < 4; ++u) {
        const int t = itr * 4 + u;
        const char* bb = sL[t & 1];
        if (t + 4 < DN_STEPS) LOAD(aS[u][0], aS[u][1], bS[u]);
        s16x8 af0 = *(const s16x8*)(bb + aoffs[0]);
        s16x8 af1 = *(const s16x8*)(bb + aoffs[1]);
        s16x8 bf[8];
#pragma unroll
        for (int nf = 0; nf < 8; ++nf) {
          const char* p = bb + boffs[nf];
          union { uint32_t u4[4]; s16x8 v; } w;
          w.u4[0] = *(const uint32_t*)p;
          w.u4[1] = *(const uint32_t*)(p + 528);
          w.u4[2] = *(const uint32_t*)(p + 1056);
          w.u4[3] = *(const uint32_t*)(p + 1584);
          bf[nf] = w.v;
        }
        WAIT_LGKM0();
        barrier_raw();
        if (t + 1 < DN_STEPS)
          WRITE((t + 1) & 1, aS[(u + 1) & 3][0], aS[(u + 1) & 3][1], bS[(u + 1) & 3]);
        WAIT_LGKM0();
        barrier_raw();
#pragma unroll
        for (int nf = 0; nf < 8; ++nf) {
          acc[0][nf] = __builtin_amdgcn_mfma_f32_16x16x32_bf16(af0, bf[nf], acc[0][nf], 0, 0, 0);
          acc[1][nf] = __builtin_amdgcn_mfma_f32_16x16x32_bf16(af1, bf[nf], acc[1][nf], 0, 0, 0);
        }
      }
    }

    // epilogue: fp32 atomic scatter into Out
#pragma unroll
    for (int mi = 0; mi < 2; ++mi) {
      const int rb = wid * 32 + mi * 16 + m * 4;
      const int4 tk4 = *(const int4*)&tokl[tbase + rb];
      const int tks[4] = {tk4.x, tk4.y, tk4.z, tk4.w};
#pragma unroll
      for (int r = 0; r < 4; ++r) {
        const int row = rb + r;
        if (row < nrows) {
          float* op = Out + (size_t)tks[r] * HDIM + hb + c;
#pragma unroll
          for (int nf = 0; nf < 8; ++nf)
            atomicAdd(op + nf * 16, acc[mi][nf][r]);
        }
      }
    }
  }
}

extern "C" void kernel_launch(void* const* d_in, const int* in_sizes, int n_in,
                              void* d_out, int out_size, void* d_ws, size_t ws_size,
                              hipStream_t stream) {
  (void)in_sizes; (void)n_in; (void)ws_size;
  const float* X  = (const float*)d_in[0];
  const float* GW = (const float*)d_in[1];
  const float* WG = (const float*)d_in[2];
  const float* WU = (const float*)d_in[3];
  const float* WD = (const float*)d_in[4];
  float* Out = (float*)d_out;
  char* ws = (char*)d_ws;

  __hip_bfloat16* Xb = (__hip_bfloat16*)(ws + XBF_OFF);
  int*   cnt  = (int*)(ws + CNT_OFF);
  int*   offs = (int*)(ws + OFF_OFF);
  int*   qm   = (int*)(ws + QM_OFF);
  int*   rgl  = (int*)(ws + RGL_OFF);
  int*   tokl = (int*)(ws + TOK_OFF);
  float* wtl  = (float*)(ws + WT_OFF);
  __hip_bfloat16* Hh = (__hip_bfloat16*)(ws + HH_OFF);

  hipMemsetAsync(ws + CNT_OFF, 0, 1024, stream);  // cnt + offs + queues
  hipMemsetAsync(d_out, 0, (size_t)out_size * sizeof(float), stream);

  router_kernel<<<T_TOK, 256, 0, stream>>>(X, GW, Xb, cnt, tokl, wtl);
  scan_kernel<<<1, 64, 0, stream>>>(cnt, offs, rgl, qm);
  gateup_kernel<<<512, 256, 0, stream>>>(Xb, WG, WU, cnt, offs, tokl, wtl, Hh, qm, rgl);
  down_kernel<<<512, 256, 0, stream>>>(Hh, WD, cnt, offs, tokl, Out, qm, rgl);
}

// Round 8
// 564.565 us; speedup vs baseline: 1.7385x; 1.7385x over previous
//
#include <hip/hip_runtime.h>
#include <hip/hip_bf16.h>
#include <cstddef>
#include <cstdint>

#define T_TOK 1024
#define HDIM  2048
#define NEXP  64
#define IDIM  768
#define TOPK  8

using f32x4 = __attribute__((ext_vector_type(4))) float;
using s16x8 = __attribute__((ext_vector_type(8))) short;

// ---- workspace layout (bytes) ----
static constexpr size_t XBF_OFF = 0;                                   // bf16 X: 4 MiB
static constexpr size_t CNT_OFF = (size_t)T_TOK * HDIM * 2;            // 64 ints
static constexpr size_t OFF_OFF = CNT_OFF + 256;                       // 65 ints
static constexpr size_t QM_OFF  = CNT_OFF + 768;                       // q_gu, q_dn, nrg
static constexpr size_t RGL_OFF = CNT_OFF + 1024;                      // rowgroup list
static constexpr size_t TOK_OFF = CNT_OFF + 4096;                      // 64*1024 ints
static constexpr size_t WT_OFF  = TOK_OFF + (size_t)NEXP * T_TOK * 4;  // 64*1024 floats
static constexpr size_t HH_OFF  = WT_OFF  + (size_t)NEXP * T_TOK * 4;  // 8192*768 bf16

__device__ __forceinline__ short f2bf(float f) {
  union { __hip_bfloat16 b; short s; } u;
  u.b = __float2bfloat16(f);
  return u.s;
}
__device__ __forceinline__ uint32_t pk2(float lo, float hi) {
  return ((uint32_t)(uint16_t)f2bf(hi) << 16) | (uint16_t)f2bf(lo);
}
__device__ __forceinline__ void barrier_raw() {
  asm volatile("" ::: "memory");
  __builtin_amdgcn_s_barrier();
  asm volatile("" ::: "memory");
}
#define WAIT_LGKM0() asm volatile("s_waitcnt lgkmcnt(0)" ::: "memory")

// ---------------- router (+ fused fp32->bf16 convert of X) ----------------
__global__ __launch_bounds__(256) void router_kernel(
    const float* __restrict__ X, const float* __restrict__ GW,
    __hip_bfloat16* __restrict__ Xb,
    int* __restrict__ cnt, int* __restrict__ tokl, float* __restrict__ wtl) {
  __shared__ float xs[HDIM];
  __shared__ float lg[NEXP];
  const int t = blockIdx.x;
  const int tid = threadIdx.x;
  const f32x4* xr = (const f32x4*)(X + (size_t)t * HDIM);
#pragma unroll
  for (int i = 0; i < 2; ++i) {
    f32x4 v = xr[tid + i * 256];
    *(f32x4*)&xs[(tid + i * 256) * 4] = v;
  }
  __syncthreads();
  {
    union { short h[8]; int4 q; } u;
#pragma unroll
    for (int j = 0; j < 8; ++j) u.h[j] = f2bf(xs[tid * 8 + j]);
    *(int4*)((char*)Xb + ((size_t)t * HDIM + tid * 8) * 2) = u.q;
  }
  const int wid = tid >> 6, lane = tid & 63;
  for (int ee = 0; ee < 16; ++ee) {
    const int e = wid * 16 + ee;
    const float* g = GW + (size_t)e * HDIM;
    float acc = 0.f;
    for (int i = lane; i < HDIM; i += 64) acc += xs[i] * g[i];
#pragma unroll
    for (int s = 32; s; s >>= 1) acc += __shfl_xor(acc, s);
    if (lane == 0) lg[e] = acc;
  }
  __syncthreads();
  if (tid < 64) {
    const float v = lg[tid];
    float m = v;
#pragma unroll
    for (int s = 32; s; s >>= 1) m = fmaxf(m, __shfl_xor(m, s));
    const float p = expf(v - m);
    float den = p;
#pragma unroll
    for (int s = 32; s; s >>= 1) den += __shfl_xor(den, s);
    float work = p / den;
    float my_v = 0.f; int my_e = 0;
    float topsum = 0.f;
#pragma unroll
    for (int k = 0; k < TOPK; ++k) {
      float mv = work;
#pragma unroll
      for (int s = 32; s; s >>= 1) mv = fmaxf(mv, __shfl_xor(mv, s));
      unsigned long long ball = __ballot(work == mv);
      const int idx = __ffsll(ball) - 1;   // lowest index on ties (matches lax.top_k)
      topsum += mv;
      if (tid == k) { my_v = mv; my_e = idx; }
      if (tid == idx) work = -1.f;
    }
    if (tid < TOPK) {
      const float w = my_v / topsum;
      const int slot = atomicAdd(&cnt[my_e], 1);
      tokl[my_e * T_TOK + slot] = t;
      wtl[my_e * T_TOK + slot] = w;
    }
  }
}

// ---------------- prefix scan + rowgroup list ----------------
__global__ void scan_kernel(const int* __restrict__ cnt, int* __restrict__ offs,
                            int* __restrict__ rgl, int* __restrict__ qm) {
  if (threadIdx.x == 0) {
    int a = 0, nrg = 0;
    for (int e = 0; e < NEXP; ++e) {
      offs[e] = a;
      const int ne = cnt[e];
      a += ne;
      for (int t = 0; t * 128 < ne; ++t) rgl[nrg++] = (e << 3) | t;
    }
    offs[NEXP] = a;
    qm[2] = nrg;
  }
}

// ===== named-register staging macros (two-level paste; NO lambdas/arrays) ====
#define GU_LOADSET_(S)                                     \
    a0_##S = *(const int4*)pa0;                            \
    a1_##S = *(const int4*)pa1;                            \
    pa0 += 32; pa1 += 32;                                  \
    b0_##S = *(const f32x4*)(pb);                          \
    b1_##S = *(const f32x4*)(pb + IDIM);                   \
    b2_##S = *(const f32x4*)(pb + 2 * IDIM);               \
    b3_##S = *(const f32x4*)(pb + 3 * IDIM);               \
    pb += (size_t)32 * IDIM;
#define GU_LOADSET(S) GU_LOADSET_(S)

#define GU_WRITESET_(S, BUF) {                             \
    char* base_ = sL[BUF];                                 \
    *(int4*)(base_ + adst) = a0_##S;                       \
    *(int4*)(base_ + adst + 1024) = a1_##S;                \
    union { uint32_t u[4]; int4 q; } d0_, d1_;             \
    d0_.u[0] = pk2(b0_##S[0], b1_##S[0]);                  \
    d0_.u[1] = pk2(b0_##S[1], b1_##S[1]);                  \
    d0_.u[2] = pk2(b0_##S[2], b1_##S[2]);                  \
    d0_.u[3] = pk2(b0_##S[3], b1_##S[3]);                  \
    d1_.u[0] = pk2(b2_##S[0], b3_##S[0]);                  \
    d1_.u[1] = pk2(b2_##S[1], b3_##S[1]);                  \
    d1_.u[2] = pk2(b2_##S[2], b3_##S[2]);                  \
    d1_.u[3] = pk2(b2_##S[3], b3_##S[3]);                  \
    *(int4*)(base_ + bdst) = d0_.q;                        \
    *(int4*)(base_ + bdst + 272) = d1_.q; }
#define GU_WRITESET(S, BUF) GU_WRITESET_(S, BUF)

#define GU_STEP(LS, WS, RB, WB, DO_LOAD, DO_WRITE) {       \
    if (DO_LOAD) { GU_LOADSET(LS) }                        \
    const char* bb_ = sL[RB];                              \
    s16x8 af0 = *(const s16x8*)(bb_ + aoff0);              \
    s16x8 af1 = *(const s16x8*)(bb_ + aoff1);              \
    s16x8 bf[2][4];                                        \
    _Pragma("unroll") for (int mt = 0; mt < 2; ++mt)       \
    _Pragma("unroll") for (int nf = 0; nf < 4; ++nf) {     \
      const char* p_ = bb_ + boffs[mt][nf];                \
      union { uint32_t u[4]; s16x8 v; } w_;                \
      w_.u[0] = *(const uint32_t*)p_;                      \
      w_.u[1] = *(const uint32_t*)(p_ + 272);              \
      w_.u[2] = *(const uint32_t*)(p_ + 544);              \
      w_.u[3] = *(const uint32_t*)(p_ + 816);              \
      bf[mt][nf] = w_.v; }                                 \
    WAIT_LGKM0();                                          \
    barrier_raw();                                         \
    if (DO_WRITE) { GU_WRITESET(WS, WB) WAIT_LGKM0(); }    \
    barrier_raw();                                         \
    _Pragma("unroll") for (int mt = 0; mt < 2; ++mt)       \
    _Pragma("unroll") for (int nf = 0; nf < 4; ++nf) {     \
      acc[0][mt][nf] = __builtin_amdgcn_mfma_f32_16x16x32_bf16(af0, bf[mt][nf], acc[0][mt][nf], 0, 0, 0); \
      acc[1][mt][nf] = __builtin_amdgcn_mfma_f32_16x16x32_bf16(af1, bf[mt][nf], acc[1][mt][nf], 0, 0, 0); } }

// ================= gate+up GEMM + SwiGLU =================
// item = (rowgroup, nc of 12): BM=128, BN=64 per matrix, both mats, BK=32,
// 64 steps. Depth-4 NAMED-register staging -> LDS double buffer. R7-verified
// LDS layout / fragment mapping / epilogue.
__global__ __launch_bounds__(256, 2) void gateup_kernel(
    const __hip_bfloat16* __restrict__ Xb, const float* __restrict__ WG,
    const float* __restrict__ WU, const int* __restrict__ cnt,
    const int* __restrict__ offs, const int* __restrict__ tokl,
    const float* __restrict__ wtl, __hip_bfloat16* __restrict__ Hh,
    int* __restrict__ qm, const int* __restrict__ rgl) {
  __shared__ __align__(16) char sL[2][16896];   // A 8192 + B 2*4352
  __shared__ int sItem;
  const int tid = threadIdx.x, lane = tid & 63, wid = tid >> 6;
  const int m = lane >> 4, c = lane & 15;
  const int asr  = wid * 32 + (lane >> 2);
  const int achk = (lane & 3) ^ ((lane >> 2) & 3);
  const int adst = wid * 2048 + lane * 16;
  const int bg   = (lane >> 4) & 3;
  const int bk0  = (wid & 1) * 16 + bg * 4;
  const int bdst = 8192 + (wid >> 1) * 4352 + ((wid & 1) * 8 + bg * 2) * 272 + (lane & 15) * 16;
  const int aoff0 = (wid * 32 + 0 * 16 + c) * 64 + ((m ^ (c & 3)) << 4);
  const int aoff1 = (wid * 32 + 1 * 16 + c) * 64 + ((m ^ (c & 3)) << 4);
  int boffs[2][4];
#pragma unroll
  for (int mt = 0; mt < 2; ++mt)
#pragma unroll
    for (int nf = 0; nf < 4; ++nf)
      boffs[mt][nf] = 8192 + mt * 4352 + (m * 4) * 272 + (nf * 16 + c) * 4;
  const int itot = qm[2] * 12;

  for (;;) {
    __syncthreads();
    if (tid == 0) sItem = atomicAdd(&qm[0], 1);
    __syncthreads();
    const int it = sItem;
    if (it >= itot) break;
    const int rg = rgl[it / 12];
    const int e = rg >> 3, ti = rg & 7, nc = it % 12;
    const int ne = cnt[e];
    const int nrows = min(128, ne - ti * 128);
    const int nb = nc * 64;
    const int cbase = offs[e] + ti * 128;
    const int tbase = e * T_TOK + ti * 128;

    const short* pa0 = (const short*)Xb + (size_t)tokl[tbase + min(asr, nrows - 1)] * HDIM + achk * 8;
    const short* pa1 = (const short*)Xb + (size_t)tokl[tbase + min(asr + 16, nrows - 1)] * HDIM + achk * 8;
    const float* pb = ((wid >> 1) ? WU : WG) + (size_t)e * HDIM * IDIM
                      + (size_t)bk0 * IDIM + nb + (lane & 15) * 4;

    f32x4 acc[2][2][4];
#pragma unroll
    for (int i = 0; i < 2; ++i)
#pragma unroll
      for (int mt = 0; mt < 2; ++mt)
#pragma unroll
        for (int nf = 0; nf < 4; ++nf)
#pragma unroll
          for (int r = 0; r < 4; ++r) acc[i][mt][nf][r] = 0.f;

    // named staging sets (depth 4)
    int4  a0_0, a1_0, a0_1, a1_1, a0_2, a1_2, a0_3, a1_3;
    f32x4 b0_0, b1_0, b2_0, b3_0;
    f32x4 b0_1, b1_1, b2_1, b3_1;
    f32x4 b0_2, b1_2, b2_2, b3_2;
    f32x4 b0_3, b1_3, b2_3, b3_3;

    // prologue: tiles 0..3 -> sets 0..3; tile0 -> buf0
    GU_LOADSET(0)
    GU_LOADSET(1)
    GU_LOADSET(2)
    GU_LOADSET(3)
    GU_WRITESET(0, 0)
    WAIT_LGKM0();
    barrier_raw();

    for (int itr = 0; itr < 15; ++itr) {      // t = 0..59
      GU_STEP(0, 1, 0, 1, true, true)
      GU_STEP(1, 2, 1, 0, true, true)
      GU_STEP(2, 3, 0, 1, true, true)
      GU_STEP(3, 0, 1, 0, true, true)
    }
    // tail t = 60..63
    GU_STEP(0, 1, 0, 1, false, true)
    GU_STEP(0, 2, 1, 0, false, true)
    GU_STEP(0, 3, 0, 1, false, true)
    GU_STEP(0, 0, 1, 0, false, false)

    // epilogue: h = silu(g) * u * wt -> bf16 Hh (compact rows)
#pragma unroll
    for (int mi = 0; mi < 2; ++mi) {
      const int rb = wid * 32 + mi * 16 + m * 4;
      const f32x4 wt4 = *(const f32x4*)&wtl[tbase + rb];
#pragma unroll
      for (int nf = 0; nf < 4; ++nf) {
        const int colg = nb + nf * 16 + c;
#pragma unroll
        for (int r = 0; r < 4; ++r) {
          const int row = rb + r;
          if (row < nrows) {
            const float g = acc[mi][0][nf][r], uu = acc[mi][1][nf][r];
            const float h = (g / (1.f + __expf(-g))) * uu * wt4[r];
            Hh[(size_t)(cbase + row) * IDIM + colg] = __float2bfloat16(h);
          }
        }
      }
    }
  }
}

// ===== down-kernel macros =====
#define DN_LOADSET_(S)                                     \
    a0_##S = *(const int4*)pa0;                            \
    a1_##S = *(const int4*)pa1;                            \
    pa0 += 32; pa1 += 32;                                  \
    b0_##S = *(const f32x4*)(pb);                          \
    b1_##S = *(const f32x4*)(pb + HDIM);                   \
    b2_##S = *(const f32x4*)(pb + 2 * HDIM);               \
    b3_##S = *(const f32x4*)(pb + 3 * HDIM);               \
    pb += (size_t)32 * HDIM;
#define DN_LOADSET(S) DN_LOADSET_(S)

#define DN_WRITESET_(S, BUF) {                             \
    char* base_ = sL[BUF];                                 \
    *(int4*)(base_ + adst) = a0_##S;                       \
    *(int4*)(base_ + adst + 1024) = a1_##S;                \
    union { uint32_t u[4]; int4 q; } d0_, d1_;             \
    d0_.u[0] = pk2(b0_##S[0], b1_##S[0]);                  \
    d0_.u[1] = pk2(b0_##S[1], b1_##S[1]);                  \
    d0_.u[2] = pk2(b0_##S[2], b1_##S[2]);                  \
    d0_.u[3] = pk2(b0_##S[3], b1_##S[3]);                  \
    d1_.u[0] = pk2(b2_##S[0], b3_##S[0]);                  \
    d1_.u[1] = pk2(b2_##S[1], b3_##S[1]);                  \
    d1_.u[2] = pk2(b2_##S[2], b3_##S[2]);                  \
    d1_.u[3] = pk2(b2_##S[3], b3_##S[3]);                  \
    *(int4*)(base_ + bdst) = d0_.q;                        \
    *(int4*)(base_ + bdst + 528) = d1_.q; }
#define DN_WRITESET(S, BUF) DN_WRITESET_(S, BUF)

#define DN_STEP(LS, WS, RB, WB, DO_LOAD, DO_WRITE) {       \
    if (DO_LOAD) { DN_LOADSET(LS) }                        \
    const char* bb_ = sL[RB];                              \
    s16x8 af0 = *(const s16x8*)(bb_ + aoff0);              \
    s16x8 af1 = *(const s16x8*)(bb_ + aoff1);              \
    s16x8 bf[8];                                           \
    _Pragma("unroll") for (int nf = 0; nf < 8; ++nf) {     \
      const char* p_ = bb_ + boffs[nf];                    \
      union { uint32_t u[4]; s16x8 v; } w_;                \
      w_.u[0] = *(const uint32_t*)p_;                      \
      w_.u[1] = *(const uint32_t*)(p_ + 528);              \
      w_.u[2] = *(const uint32_t*)(p_ + 1056);             \
      w_.u[3] = *(const uint32_t*)(p_ + 1584);             \
      bf[nf] = w_.v; }                                     \
    WAIT_LGKM0();                                          \
    barrier_raw();                                         \
    if (DO_WRITE) { DN_WRITESET(WS, WB) WAIT_LGKM0(); }    \
    barrier_raw();                                         \
    _Pragma("unroll") for (int nf = 0; nf < 8; ++nf) {     \
      acc[0][nf] = __builtin_amdgcn_mfma_f32_16x16x32_bf16(af0, bf[nf], acc[0][nf], 0, 0, 0); \
      acc[1][nf] = __builtin_amdgcn_mfma_f32_16x16x32_bf16(af1, bf[nf], acc[1][nf], 0, 0, 0); } }

// ================= down GEMM + scatter =================
// item = (rowgroup, hc of 16): BM=128, BN=128, BK=32, 24 steps.
__global__ __launch_bounds__(256, 2) void down_kernel(
    const __hip_bfloat16* __restrict__ Hh, const float* __restrict__ WD,
    const int* __restrict__ cnt, const int* __restrict__ offs,
    const int* __restrict__ tokl, float* __restrict__ Out,
    int* __restrict__ qm, const int* __restrict__ rgl) {
  __shared__ __align__(16) char sL[2][16640];   // A 8192 + B 16*528
  __shared__ int sItem;
  const int tid = threadIdx.x, lane = tid & 63, wid = tid >> 6;
  const int m = lane >> 4, c = lane & 15;
  const int asr  = wid * 32 + (lane >> 2);
  const int achk = (lane & 3) ^ ((lane >> 2) & 3);
  const int adst = wid * 2048 + lane * 16;
  const int bg   = (lane >> 5) & 1;
  const int bdst = 8192 + (wid * 4 + bg * 2) * 528 + (lane & 31) * 16;
  const int aoff0 = (wid * 32 + 0 * 16 + c) * 64 + ((m ^ (c & 3)) << 4);
  const int aoff1 = (wid * 32 + 1 * 16 + c) * 64 + ((m ^ (c & 3)) << 4);
  int boffs[8];
#pragma unroll
  for (int nf = 0; nf < 8; ++nf)
    boffs[nf] = 8192 + (m * 4) * 528 + (nf * 16 + c) * 4;
  const int itot = qm[2] * 16;

  for (;;) {
    __syncthreads();
    if (tid == 0) sItem = atomicAdd(&qm[1], 1);
    __syncthreads();
    const int it = sItem;
    if (it >= itot) break;
    const int rg = rgl[it >> 4];
    const int e = rg >> 3, ti = rg & 7, hc = it & 15;
    const int ne = cnt[e];
    const int nrows = min(128, ne - ti * 128);
    const int hb = hc * 128;
    const int cbase = offs[e] + ti * 128;
    const int tbase = e * T_TOK + ti * 128;

    const short* pa0 = (const short*)Hh + (size_t)(cbase + min(asr, nrows - 1)) * IDIM + achk * 8;
    const short* pa1 = (const short*)Hh + (size_t)(cbase + min(asr + 16, nrows - 1)) * IDIM + achk * 8;
    const float* pb = WD + (size_t)e * IDIM * HDIM
                      + (size_t)(wid * 8 + bg * 4) * HDIM + hb + (lane & 31) * 4;

    f32x4 acc[2][8];
#pragma unroll
    for (int i = 0; i < 2; ++i)
#pragma unroll
      for (int nf = 0; nf < 8; ++nf)
#pragma unroll
        for (int r = 0; r < 4; ++r) acc[i][nf][r] = 0.f;

    int4  a0_0, a1_0, a0_1, a1_1, a0_2, a1_2, a0_3, a1_3;
    f32x4 b0_0, b1_0, b2_0, b3_0;
    f32x4 b0_1, b1_1, b2_1, b3_1;
    f32x4 b0_2, b1_2, b2_2, b3_2;
    f32x4 b0_3, b1_3, b2_3, b3_3;

    DN_LOADSET(0)
    DN_LOADSET(1)
    DN_LOADSET(2)
    DN_LOADSET(3)
    DN_WRITESET(0, 0)
    WAIT_LGKM0();
    barrier_raw();

    for (int itr = 0; itr < 5; ++itr) {       // t = 0..19
      DN_STEP(0, 1, 0, 1, true, true)
      DN_STEP(1, 2, 1, 0, true, true)
      DN_STEP(2, 3, 0, 1, true, true)
      DN_STEP(3, 0, 1, 0, true, true)
    }
    // tail t = 20..23
    DN_STEP(0, 1, 0, 1, false, true)
    DN_STEP(0, 2, 1, 0, false, true)
    DN_STEP(0, 3, 0, 1, false, true)
    DN_STEP(0, 0, 1, 0, false, false)

    // epilogue: fp32 atomic scatter into Out
#pragma unroll
    for (int mi = 0; mi < 2; ++mi) {
      const int rb = wid * 32 + mi * 16 + m * 4;
      const int4 tk4 = *(const int4*)&tokl[tbase + rb];
      const int tks[4] = {tk4.x, tk4.y, tk4.z, tk4.w};
#pragma unroll
      for (int r = 0; r < 4; ++r) {
        const int row = rb + r;
        if (row < nrows) {
          float* op = Out + (size_t)tks[r] * HDIM + hb + c;
#pragma unroll
          for (int nf = 0; nf < 8; ++nf)
            atomicAdd(op + nf * 16, acc[mi][nf][r]);
        }
      }
    }
  }
}

extern "C" void kernel_launch(void* const* d_in, const int* in_sizes, int n_in,
                              void* d_out, int out_size, void* d_ws, size_t ws_size,
                              hipStream_t stream) {
  (void)in_sizes; (void)n_in; (void)ws_size;
  const float* X  = (const float*)d_in[0];
  const float* GW = (const float*)d_in[1];
  const float* WG = (const float*)d_in[2];
  const float* WU = (const float*)d_in[3];
  const float* WD = (const float*)d_in[4];
  float* Out = (float*)d_out;
  char* ws = (char*)d_ws;

  __hip_bfloat16* Xb = (__hip_bfloat16*)(ws + XBF_OFF);
  int*   cnt  = (int*)(ws + CNT_OFF);
  int*   offs = (int*)(ws + OFF_OFF);
  int*   qm   = (int*)(ws + QM_OFF);
  int*   rgl  = (int*)(ws + RGL_OFF);
  int*   tokl = (int*)(ws + TOK_OFF);
  float* wtl  = (float*)(ws + WT_OFF);
  __hip_bfloat16* Hh = (__hip_bfloat16*)(ws + HH_OFF);

  hipMemsetAsync(ws + CNT_OFF, 0, 1024, stream);  // cnt + offs + queues
  hipMemsetAsync(d_out, 0, (size_t)out_size * sizeof(float), stream);

  router_kernel<<<T_TOK, 256, 0, stream>>>(X, GW, Xb, cnt, tokl, wtl);
  scan_kernel<<<1, 64, 0, stream>>>(cnt, offs, rgl, qm);
  gateup_kernel<<<512, 256, 0, stream>>>(Xb, WG, WU, cnt, offs, tokl, wtl, Hh, qm, rgl);
  down_kernel<<<512, 256, 0, stream>>>(Hh, WD, cnt, offs, tokl, Out, qm, rgl);
}